// Round 6
// baseline (226.185 us; speedup 1.0000x reference)
//
#include <hip/hip_runtime.h>
#include <hip/hip_bf16.h>

#define VNUM 6890
#define KJ 24
#define NBETA 10
#define NPOSE 207
#define KPAD 224        // NPOSE padded to 7*32; cols 207..216 carry betas/sd
#define BATCH 1024
#define N3 20670        // VNUM*3
#define N3PAD 20672     // 323*64
#define VPAD 6912       // 432*16

// d_out element offsets (f32 elements)
#define OUT_V  0
#define OUT_JT 21166080
#define OUT_J  21239808
#define OUT_RM 21313536

// ws offsets (float units)
#define WS_JVJS 0                 // 792 floats
#define WS_ABF  792               // ushort[1024*480]  = 245760 f -> ends 246552
#define WS_WBF  246552            // ushort[6912*40]   = 138240 f -> ends 384792
#define WS_PFB  384792            // ushort[1024*224]  = 114688 f -> ends 499480
#define WS_PDT  499480            // ushort[20672*224] = 2315264 f -> ends 2814744

typedef unsigned short ushort;
typedef __attribute__((ext_vector_type(8))) short short8v;
typedef __attribute__((ext_vector_type(4))) float floatx4;

__device__ __forceinline__ ushort f2bfu(float x) {
  __hip_bfloat16 h = __float2bfloat16(x);
  union { __hip_bfloat16 h; ushort u; } cv; cv.h = h; return cv.u;
}

// ---------------------------------------------------------------------------
// Kernel 0: JvJs accumulation, split over 4 V-chunks, atomicAdd combine.
// ---------------------------------------------------------------------------
__global__ __launch_bounds__(256) void jreg_kernel(
    const float* __restrict__ Jr, const float* __restrict__ vt,
    const float* __restrict__ sd, float* __restrict__ JvJs) {
  const int j = blockIdx.x;
  const int chunk = blockIdx.y;
  const int t = threadIdx.x;
  const int lane = t & 63, wid = t >> 6;
  const int vbeg = chunk * 1723;
  const int vend = (vbeg + 1723 < VNUM) ? vbeg + 1723 : VNUM;
  __shared__ float red[4][33];
  float acc[33];
#pragma unroll
  for (int q = 0; q < 33; q++) acc[q] = 0.0f;
  for (int v = vbeg + t; v < vend; v += 256) {
    float r = Jr[j * VNUM + v];
    const float* vtp = vt + v * 3;
    const float* sdp = sd + v * 30;
    acc[0] += r * vtp[0];
    acc[1] += r * vtp[1];
    acc[2] += r * vtp[2];
#pragma unroll
    for (int q = 0; q < 30; q++) acc[3 + q] += r * sdp[q];
  }
#pragma unroll
  for (int q = 0; q < 33; q++) {
    float x = acc[q];
    for (int off = 32; off > 0; off >>= 1) x += __shfl_down(x, off, 64);
    if (lane == 0) red[wid][q] = x;
  }
  __syncthreads();
  if (t < 33)
    atomicAdd(&JvJs[j * 33 + t], red[0][t] + red[1][t] + red[2][t] + red[3][t]);
}

// ---------------------------------------------------------------------------
// Kernel 1: per-batch: rodrigues, joints_t, pose_feature+betas (bf16), chain,
// A written directly as bf16 in MFMA layout: Abf[b][n(12)][k(40)], k>=24 zero.
// pfb row layout: [0..206]=pose_feature, [207..216]=betas, [217..223]=0.
// ---------------------------------------------------------------------------
__global__ __launch_bounds__(64) void batch_prep(
    const float* __restrict__ body_pose, const float* __restrict__ betas,
    const float* __restrict__ global_orient, const float* __restrict__ JvJs,
    float* __restrict__ out_jt, float* __restrict__ out_j, float* __restrict__ out_rm,
    ushort* __restrict__ pfb, ushort* __restrict__ Abf) {
  const int b = blockIdx.x;
  const int t = threadIdx.x;
  __shared__ float R[24][9];
  __shared__ float jt[24][3];
  __shared__ float chR[24][9];
  __shared__ float cht[24][3];

  if (t < 24) {
    float ax, ay, az;
    if (t == 0) {
      ax = global_orient[b * 3 + 0];
      ay = global_orient[b * 3 + 1];
      az = global_orient[b * 3 + 2];
    } else {
      const float* p = body_pose + (size_t)b * 69 + (t - 1) * 3;
      ax = p[0]; ay = p[1]; az = p[2];
    }
    float px = ax + 1e-8f, py = ay + 1e-8f, pz = az + 1e-8f;
    float angle = sqrtf(px * px + py * py + pz * pz);
    float inv = 1.0f / angle;
    float rx = ax * inv, ry = ay * inv, rz = az * inv;
    float s = sinf(angle), c = cosf(angle);
    float cc = 1.0f - c;
    float m[9];
    m[0] = 1.0f - cc * (ry * ry + rz * rz);
    m[1] = -s * rz + cc * rx * ry;
    m[2] =  s * ry + cc * rx * rz;
    m[3] =  s * rz + cc * rx * ry;
    m[4] = 1.0f - cc * (rx * rx + rz * rz);
    m[5] = -s * rx + cc * ry * rz;
    m[6] = -s * ry + cc * rx * rz;
    m[7] =  s * rx + cc * ry * rz;
    m[8] = 1.0f - cc * (rx * rx + ry * ry);
#pragma unroll
    for (int e = 0; e < 9; e++) {
      R[t][e] = m[e];
      out_rm[(size_t)b * 216 + t * 9 + e] = m[e];
    }
  }
  for (int idx = t; idx < 72; idx += 64) {
    int j = idx / 3, c = idx % 3;
    const float* JJ = JvJs + j * 33;
    float s = JJ[c];
    const float* be = betas + (size_t)b * NBETA;
#pragma unroll
    for (int l = 0; l < NBETA; l++) s += be[l] * JJ[3 + c * 10 + l];
    jt[j][c] = s;
    out_jt[(size_t)b * 72 + idx] = s;
  }
  __syncthreads();
  for (int mI = t; mI < KPAD; mI += 64) {
    float val = 0.0f;
    if (mI < NPOSE) {
      int k = 1 + mI / 9, e = mI % 9;
      val = R[k][e] - ((e == 0 || e == 4 || e == 8) ? 1.0f : 0.0f);
    } else if (mI < NPOSE + NBETA) {
      val = betas[(size_t)b * NBETA + (mI - NPOSE)];
    }
    pfb[(size_t)b * KPAD + mI] = f2bfu(val);
  }
  if (t == 0) {
    const int par[24] = {-1, 0, 0, 0, 1, 2, 3, 4, 5, 6, 7, 8, 9, 9, 9, 12, 13, 14, 16, 17, 18, 19, 20, 21};
#pragma unroll
    for (int e = 0; e < 9; e++) chR[0][e] = R[0][e];
    cht[0][0] = jt[0][0]; cht[0][1] = jt[0][1]; cht[0][2] = jt[0][2];
    for (int k = 1; k < 24; k++) {
      int p = par[k];
      float rel0 = jt[k][0] - jt[p][0];
      float rel1 = jt[k][1] - jt[p][1];
      float rel2 = jt[k][2] - jt[p][2];
#pragma unroll
      for (int i = 0; i < 3; i++) {
        float a0 = chR[p][i * 3 + 0], a1 = chR[p][i * 3 + 1], a2 = chR[p][i * 3 + 2];
        chR[k][i * 3 + 0] = a0 * R[k][0] + a1 * R[k][3] + a2 * R[k][6];
        chR[k][i * 3 + 1] = a0 * R[k][1] + a1 * R[k][4] + a2 * R[k][7];
        chR[k][i * 3 + 2] = a0 * R[k][2] + a1 * R[k][5] + a2 * R[k][8];
        cht[k][i] = a0 * rel0 + a1 * rel1 + a2 * rel2 + cht[p][i];
      }
    }
  }
  __syncthreads();
  if (t < 24) {
    int k = t;
#pragma unroll
    for (int i = 0; i < 3; i++) out_j[(size_t)b * 72 + k * 3 + i] = cht[k][i];
  }
  // A in bf16, layout: Abf[b*480 + n*40 + k], n = i*4+j
  for (int e = t; e < 480; e += 64) {
    int n = e / 40, k = e - (e / 40) * 40;
    float val = 0.0f;
    if (k < 24) {
      int i = n >> 2, jj = n & 3;
      if (jj < 3) {
        val = chR[k][i * 3 + jj];
      } else {
        val = cht[k][i] - (chR[k][i * 3 + 0] * jt[k][0] +
                           chR[k][i * 3 + 1] * jt[k][1] +
                           chR[k][i * 3 + 2] * jt[k][2]);
      }
    }
    Abf[(size_t)b * 480 + e] = f2bfu(val);
  }
}

// ---------------------------------------------------------------------------
// Kernel 2: pdT[n][k] = bf16(pd[k][n]) for k<207; k in 207..216 = sd[n][k-207];
// k>=217 zero. 1080 of the 2261 blocks also convert lbs_weights -> bf16 [VPAD][40].
// ---------------------------------------------------------------------------
__global__ __launch_bounds__(256) void transpose_pd(
    const float* __restrict__ pd, ushort* __restrict__ pdT,
    const float* __restrict__ sd,
    const float* __restrict__ w, ushort* __restrict__ wbf) {
  {
    int lb = blockIdx.y * 323 + blockIdx.x;
    if (lb < 1080) {
      int i = lb * 256 + threadIdx.x;          // < 6912*40 = 276480 exactly
      int v = i / 40, k = i - v * 40;
      float x = (v < VNUM && k < 24) ? w[v * 24 + k] : 0.0f;
      wbf[i] = f2bfu(x);
    }
  }
  __shared__ float tile[32][65];
  const int t = threadIdx.x;
  const int n0 = blockIdx.x * 64;
  const int k0 = blockIdx.y * 32;
  const int c = t & 63;
  for (int r = t >> 6; r < 32; r += 4) {
    int k = k0 + r, n = n0 + c;
    float x = 0.0f;
    if (n < N3) {
      if (k < NPOSE) x = pd[(size_t)k * N3 + n];
      else if (k < NPOSE + NBETA) x = sd[(size_t)n * 10 + (k - NPOSE)];
    }
    tile[r][c] = x;
  }
  __syncthreads();
  const int n = t >> 2;
  const int j0 = (t & 3) * 8;
  unsigned int outw[4];
#pragma unroll
  for (int jj = 0; jj < 4; jj++) {
    unsigned int lo = f2bfu(tile[j0 + jj * 2][n]);
    unsigned int hi = f2bfu(tile[j0 + jj * 2 + 1][n]);
    outw[jj] = lo | (hi << 16);
  }
  *(uint4*)&pdT[(size_t)(n0 + n) * KPAD + k0 + j0] =
      make_uint4(outw[0], outw[1], outw[2], outw[3]);
}

// ---------------------------------------------------------------------------
// Kernel 3 (fused, v3): per block = 2 INDEPENDENT waves, each 16 batches x
// 16 vertices. No LDS staging, no __syncthreads: B-fragments read straight
// from global pdT (L2-hot; 64B segments per row), vpS is the only LDS
// (6.4 KB) -> launch_bounds(128,8) targets VGPR<=64, 32 waves/CU, pure TLP.
// Bijective XCD swizzle: nwg = 13792 = 8*1724 exactly; logical chunk of
// 1724 consecutive blocks per XCD -> each pdT tile fetched by ~1 XCD.
// Phase 1: acc[3] = pf_ext(16 rows) @ pdT_ext(48 cols) + vt -> vpS (wave-priv).
// Phase 2: per batch i, T^T = mfma(Abf_frag, wf); apply from vpS; store once.
// ---------------------------------------------------------------------------
__global__ __launch_bounds__(128, 8) void fused_mfma(
    const ushort* __restrict__ pfb, const ushort* __restrict__ pdT,
    const float* __restrict__ vt, const ushort* __restrict__ wbf,
    const ushort* __restrict__ Abf, float* __restrict__ out_v) {
  __shared__ float vpS[32 * 50];                   // 6400 B, wave-private halves
  const int tid = threadIdx.x;
  const int lane = tid & 63, wv = tid >> 6;        // wv 0..1
  const int l15 = lane & 15, quad = lane >> 4;

  // XCD swizzle: hw xcd = blockIdx.x % 8; give each xcd a contiguous chunk
  const int bid = blockIdx.x;                      // grid = 13792 blocks 1-D
  const int L = (bid & 7) * 1724 + (bid >> 3);
  const int bm = (L & 31) * 32 + wv * 16;          // this wave's 16 batches
  const int v0 = (L >> 5) * 16;                    // vertex group

  // Phase-1 operand rows (B rows clamped into pdT's padded range)
  const int gn0 = v0 * 3 + l15;
  int r0 = gn0;       if (r0 >= N3PAD) r0 = 0;
  int r1 = gn0 + 16;  if (r1 >= N3PAD) r1 = 0;
  int r2 = gn0 + 32;  if (r2 >= N3PAD) r2 = 0;
  const ushort* ap  = pfb + (size_t)(bm + l15) * KPAD + quad * 8;
  const ushort* bp0 = pdT + (size_t)r0 * KPAD + quad * 8;
  const ushort* bp1 = pdT + (size_t)r1 * KPAD + quad * 8;
  const ushort* bp2 = pdT + (size_t)r2 * KPAD + quad * 8;

  floatx4 acc0 = {0.0f, 0.0f, 0.0f, 0.0f};
  floatx4 acc1 = acc0, acc2 = acc0;
#pragma unroll
  for (int kb = 0; kb < 7; kb++) {
    short8v a  = *(const short8v*)(ap  + kb * 32);
    short8v b0 = *(const short8v*)(bp0 + kb * 32);
    short8v b1 = *(const short8v*)(bp1 + kb * 32);
    short8v b2 = *(const short8v*)(bp2 + kb * 32);
    acc0 = __builtin_amdgcn_mfma_f32_16x16x32_bf16(a, b0, acc0, 0, 0, 0);
    acc1 = __builtin_amdgcn_mfma_f32_16x16x32_bf16(a, b1, acc1, 0, 0, 0);
    acc2 = __builtin_amdgcn_mfma_f32_16x16x32_bf16(a, b2, acc2, 0, 0, 0);
  }

  // vt epilogue values for this lane's three columns
  float vt0 = (gn0      < N3) ? vt[gn0]      : 0.0f;
  float vt1 = (gn0 + 16 < N3) ? vt[gn0 + 16] : 0.0f;
  float vt2 = (gn0 + 32 < N3) ? vt[gn0 + 32] : 0.0f;

  float* myvp = &vpS[wv * 16 * 50];
#pragma unroll
  for (int r = 0; r < 4; r++) {
    int row = quad * 4 + r;
    myvp[row * 50 +      l15] = acc0[r] + vt0;
    myvp[row * 50 + 16 + l15] = acc1[r] + vt1;
    myvp[row * 50 + 32 + l15] = acc2[r] + vt2;
  }
  // Wave-private handoff: this wave's ds_writes complete before its reads.
  __builtin_amdgcn_sched_barrier(0);
  __builtin_amdgcn_s_waitcnt(0xc07f);   // lgkmcnt(0)
  __builtin_amdgcn_sched_barrier(0);

  // Phase 2: blend for this wave's 16 batches
  const short8v wf = *(const short8v*)(wbf + (size_t)(v0 + l15) * 40 + quad * 8);
  const int gv = v0 + l15;
  const bool active = (quad < 3) && (gv < VNUM);
  const size_t vbase = (size_t)gv * 3;
  const ushort* abase = Abf + (size_t)bm * 480 + l15 * 40 + quad * 8;

  short8v apre[4];
#pragma unroll
  for (int i = 0; i < 4; i++) apre[i] = *(const short8v*)(abase + i * 480);

  const floatx4 zero = {0.0f, 0.0f, 0.0f, 0.0f};
#pragma unroll
  for (int i = 0; i < 16; i++) {
    short8v afrag = apre[i & 3];
    if (i < 12) apre[i & 3] = *(const short8v*)(abase + (i + 4) * 480);
    floatx4 t = zero;
    t = __builtin_amdgcn_mfma_f32_16x16x32_bf16(afrag, wf, t, 0, 0, 0);
    float px = myvp[i * 50 + 3 * l15 + 0];
    float py = myvp[i * 50 + 3 * l15 + 1];
    float pz = myvp[i * 50 + 3 * l15 + 2];
    if (active) {
      out_v[(size_t)(bm + i) * N3 + vbase + quad] =
          t[0] * px + t[1] * py + t[2] * pz + t[3];
    }
  }
}

extern "C" void kernel_launch(void* const* d_in, const int* in_sizes, int n_in,
                              void* d_out, int out_size, void* d_ws, size_t ws_size,
                              hipStream_t stream) {
  const float* body_pose     = (const float*)d_in[0];
  const float* betas         = (const float*)d_in[1];
  const float* global_orient = (const float*)d_in[2];
  const float* v_template    = (const float*)d_in[3];
  const float* shapedirs     = (const float*)d_in[4];
  const float* posedirs      = (const float*)d_in[5];
  const float* J_regressor   = (const float*)d_in[6];
  const float* lbs_weights   = (const float*)d_in[7];

  float* out = (float*)d_out;
  float* out_v  = out + OUT_V;
  float* out_jt = out + OUT_JT;
  float* out_j  = out + OUT_J;
  float* out_rm = out + OUT_RM;

  float* ws = (float*)d_ws;
  float* JvJs = ws + WS_JVJS;
  ushort* Abf = (ushort*)(ws + WS_ABF);
  ushort* wbf = (ushort*)(ws + WS_WBF);
  ushort* pfb = (ushort*)(ws + WS_PFB);
  ushort* pdT = (ushort*)(ws + WS_PDT);

  hipMemsetAsync(JvJs, 0, KJ * 33 * sizeof(float), stream);
  jreg_kernel<<<dim3(KJ, 4), 256, 0, stream>>>(J_regressor, v_template, shapedirs, JvJs);
  transpose_pd<<<dim3(323, 7), 256, 0, stream>>>(posedirs, pdT, shapedirs,
                                                 lbs_weights, wbf);
  batch_prep<<<BATCH, 64, 0, stream>>>(body_pose, betas, global_orient, JvJs,
                                       out_jt, out_j, out_rm, pfb, Abf);
  fused_mfma<<<13792, 128, 0, stream>>>(pfb, pdT, v_template, wbf, Abf, out_v);
}

// Round 7
// 199.900 us; speedup vs baseline: 1.1315x; 1.1315x over previous
//
#include <hip/hip_runtime.h>
#include <hip/hip_bf16.h>

#define VNUM 6890
#define KJ 24
#define NBETA 10
#define NPOSE 207
#define KPAD 224        // NPOSE padded to 7*32; cols 207..216 carry betas
#define BATCH 1024
#define N3 20670        // VNUM*3
#define NVG 431         // vertex groups of 16
#define NROWF 20688     // NVG*48 rows in pdTf
#define BATCH_TILES 32  // 1024/32

// d_out element offsets (f32 elements)
#define OUT_V  0
#define OUT_JT 21166080
#define OUT_J  21239808
#define OUT_RM 21313536

// ws offsets (float units), all 16B-aligned
#define WS_JVJS 0                 // 792 floats
#define WS_ABFF 792               // ushort[1024*512]   = 262144 f -> ends 262936
#define WS_WBFF 262936            // ushort[432*512]    = 110592 f -> ends 373528
#define WS_PFBF 373528            // ushort[64*7*512]   = 114688 f -> ends 488216
#define WS_PDTF 488216            // ushort[431*21*512] = 2317056 f -> ends 2805272

typedef unsigned short ushort;
typedef __attribute__((ext_vector_type(8))) short short8v;
typedef __attribute__((ext_vector_type(4))) float floatx4;

__device__ __forceinline__ ushort f2bfu(float x) {
  __hip_bfloat16 h = __float2bfloat16(x);
  union { __hip_bfloat16 h; ushort u; } cv; cv.h = h; return cv.u;
}

// ---------------------------------------------------------------------------
// Kernel 0: JvJs accumulation, split over 4 V-chunks, atomicAdd combine.
// ---------------------------------------------------------------------------
__global__ __launch_bounds__(256) void jreg_kernel(
    const float* __restrict__ Jr, const float* __restrict__ vt,
    const float* __restrict__ sd, float* __restrict__ JvJs) {
  const int j = blockIdx.x;
  const int chunk = blockIdx.y;
  const int t = threadIdx.x;
  const int lane = t & 63, wid = t >> 6;
  const int vbeg = chunk * 1723;
  const int vend = (vbeg + 1723 < VNUM) ? vbeg + 1723 : VNUM;
  __shared__ float red[4][33];
  float acc[33];
#pragma unroll
  for (int q = 0; q < 33; q++) acc[q] = 0.0f;
  for (int v = vbeg + t; v < vend; v += 256) {
    float r = Jr[j * VNUM + v];
    const float* vtp = vt + v * 3;
    const float* sdp = sd + v * 30;
    acc[0] += r * vtp[0];
    acc[1] += r * vtp[1];
    acc[2] += r * vtp[2];
#pragma unroll
    for (int q = 0; q < 30; q++) acc[3 + q] += r * sdp[q];
  }
#pragma unroll
  for (int q = 0; q < 33; q++) {
    float x = acc[q];
    for (int off = 32; off > 0; off >>= 1) x += __shfl_down(x, off, 64);
    if (lane == 0) red[wid][q] = x;
  }
  __syncthreads();
  if (t < 33)
    atomicAdd(&JvJs[j * 33 + t], red[0][t] + red[1][t] + red[2][t] + red[3][t]);
}

// ---------------------------------------------------------------------------
// Kernel 1: per-batch: rodrigues, joints_t, chain; writes FRAGMENT-MAJOR
// pfbf[(b>>4)*7+kb][lane*8] (lane=quad*16+(b&15)) and Abff[b][lane*8]
// (lane=quad*16+n, k=quad*8+j, n=12..15 zero).
// pose-feature row: [0..206]=pf, [207..216]=betas, [217..223]=0.
// ---------------------------------------------------------------------------
__global__ __launch_bounds__(64) void batch_prep(
    const float* __restrict__ body_pose, const float* __restrict__ betas,
    const float* __restrict__ global_orient, const float* __restrict__ JvJs,
    float* __restrict__ out_jt, float* __restrict__ out_j, float* __restrict__ out_rm,
    ushort* __restrict__ pfbf, ushort* __restrict__ Abff) {
  const int b = blockIdx.x;
  const int t = threadIdx.x;
  __shared__ float R[24][9];
  __shared__ float jt[24][3];
  __shared__ float chR[24][9];
  __shared__ float cht[24][3];

  if (t < 24) {
    float ax, ay, az;
    if (t == 0) {
      ax = global_orient[b * 3 + 0];
      ay = global_orient[b * 3 + 1];
      az = global_orient[b * 3 + 2];
    } else {
      const float* p = body_pose + (size_t)b * 69 + (t - 1) * 3;
      ax = p[0]; ay = p[1]; az = p[2];
    }
    float px = ax + 1e-8f, py = ay + 1e-8f, pz = az + 1e-8f;
    float angle = sqrtf(px * px + py * py + pz * pz);
    float inv = 1.0f / angle;
    float rx = ax * inv, ry = ay * inv, rz = az * inv;
    float s = sinf(angle), c = cosf(angle);
    float cc = 1.0f - c;
    float m[9];
    m[0] = 1.0f - cc * (ry * ry + rz * rz);
    m[1] = -s * rz + cc * rx * ry;
    m[2] =  s * ry + cc * rx * rz;
    m[3] =  s * rz + cc * rx * ry;
    m[4] = 1.0f - cc * (rx * rx + rz * rz);
    m[5] = -s * rx + cc * ry * rz;
    m[6] = -s * ry + cc * rx * rz;
    m[7] =  s * rx + cc * ry * rz;
    m[8] = 1.0f - cc * (rx * rx + ry * ry);
#pragma unroll
    for (int e = 0; e < 9; e++) {
      R[t][e] = m[e];
      out_rm[(size_t)b * 216 + t * 9 + e] = m[e];
    }
  }
  for (int idx = t; idx < 72; idx += 64) {
    int j = idx / 3, c = idx % 3;
    const float* JJ = JvJs + j * 33;
    float s = JJ[c];
    const float* be = betas + (size_t)b * NBETA;
#pragma unroll
    for (int l = 0; l < NBETA; l++) s += be[l] * JJ[3 + c * 10 + l];
    jt[j][c] = s;
    out_jt[(size_t)b * 72 + idx] = s;
  }
  __syncthreads();
  // pose-feature fragment write: k = mI, dst lane = quad*16 + (b&15)
  for (int mI = t; mI < KPAD; mI += 64) {
    float val = 0.0f;
    if (mI < NPOSE) {
      int k = 1 + mI / 9, e = mI % 9;
      val = R[k][e] - ((e == 0 || e == 4 || e == 8) ? 1.0f : 0.0f);
    } else if (mI < NPOSE + NBETA) {
      val = betas[(size_t)b * NBETA + (mI - NPOSE)];
    }
    int kb = mI >> 5, quad = (mI >> 3) & 3, j = mI & 7;
    pfbf[(size_t)(((b >> 4) * 7 + kb) * 512) + (quad * 16 + (b & 15)) * 8 + j] =
        f2bfu(val);
  }
  if (t == 0) {
    const int par[24] = {-1, 0, 0, 0, 1, 2, 3, 4, 5, 6, 7, 8, 9, 9, 9, 12, 13, 14, 16, 17, 18, 19, 20, 21};
#pragma unroll
    for (int e = 0; e < 9; e++) chR[0][e] = R[0][e];
    cht[0][0] = jt[0][0]; cht[0][1] = jt[0][1]; cht[0][2] = jt[0][2];
    for (int k = 1; k < 24; k++) {
      int p = par[k];
      float rel0 = jt[k][0] - jt[p][0];
      float rel1 = jt[k][1] - jt[p][1];
      float rel2 = jt[k][2] - jt[p][2];
#pragma unroll
      for (int i = 0; i < 3; i++) {
        float a0 = chR[p][i * 3 + 0], a1 = chR[p][i * 3 + 1], a2 = chR[p][i * 3 + 2];
        chR[k][i * 3 + 0] = a0 * R[k][0] + a1 * R[k][3] + a2 * R[k][6];
        chR[k][i * 3 + 1] = a0 * R[k][1] + a1 * R[k][4] + a2 * R[k][7];
        chR[k][i * 3 + 2] = a0 * R[k][2] + a1 * R[k][5] + a2 * R[k][8];
        cht[k][i] = a0 * rel0 + a1 * rel1 + a2 * rel2 + cht[p][i];
      }
    }
  }
  __syncthreads();
  if (t < 24) {
    int k = t;
#pragma unroll
    for (int i = 0; i < 3; i++) out_j[(size_t)b * 72 + k * 3 + i] = cht[k][i];
  }
  // Abff[b*512 + e]: e = (quad*16+n)*8+j, k = quad*8+j; n>=12 or k>=24 -> 0
  for (int e = t; e < 512; e += 64) {
    int quad = e >> 7, n = (e >> 3) & 15, j = e & 7;
    int k = quad * 8 + j;
    float val = 0.0f;
    if (n < 12 && k < 24) {
      int i = n >> 2, jj = n & 3;
      if (jj < 3) {
        val = chR[k][i * 3 + jj];
      } else {
        val = cht[k][i] - (chR[k][i * 3 + 0] * jt[k][0] +
                           chR[k][i * 3 + 1] * jt[k][1] +
                           chR[k][i * 3 + 2] * jt[k][2]);
      }
    }
    Abff[(size_t)b * 512 + e] = f2bfu(val);
  }
}

// ---------------------------------------------------------------------------
// Kernel 2: fragment-major pdTf: row r=3*vertex+c (k<207 from pd^T, 207..216
// from sd, else 0) -> pdTf[((vg*3+ns)*7+kb)*512 + (quad*16+l15)*8 + j]
// where vg=r/48, ns=(r%48)/16, l15=r%16. Grid x=324 covers 20736>=NROWF rows.
// 864 of the blocks also convert lbs_weights -> fragment-major wbff[vg][lane*8].
// ---------------------------------------------------------------------------
__global__ __launch_bounds__(256) void transpose_pd(
    const float* __restrict__ pd, ushort* __restrict__ pdTf,
    const float* __restrict__ sd,
    const float* __restrict__ w, ushort* __restrict__ wbff) {
  {
    int lb = blockIdx.y * 324 + blockIdx.x;
    if (lb < 864) {                           // 432*512/256 = 864
      int i = lb * 256 + threadIdx.x;
      int vg = i >> 9, e = i & 511;
      int quad = e >> 7, l15 = (e >> 3) & 15, j = e & 7;
      int v = vg * 16 + l15, k = quad * 8 + j;
      float x = (v < VNUM && k < 24) ? w[v * 24 + k] : 0.0f;
      wbff[i] = f2bfu(x);
    }
  }
  __shared__ float tile[32][65];
  const int t = threadIdx.x;
  const int n0 = blockIdx.x * 64;
  const int k0 = blockIdx.y * 32;
  const int c = t & 63;
  for (int r = t >> 6; r < 32; r += 4) {
    int k = k0 + r, n = n0 + c;
    float x = 0.0f;
    if (n < N3) {
      if (k < NPOSE) x = pd[(size_t)k * N3 + n];
      else if (k < NPOSE + NBETA) x = sd[(size_t)n * 10 + (k - NPOSE)];
    }
    tile[r][c] = x;
  }
  __syncthreads();
  const int n = t >> 2;               // local row 0..63
  const int j0 = (t & 3) * 8;         // k offset within 32
  const int rg = n0 + n;              // global row
  if (rg >= NROWF) return;
  unsigned int outw[4];
#pragma unroll
  for (int jj = 0; jj < 4; jj++) {
    unsigned int lo = f2bfu(tile[j0 + jj * 2][n]);
    unsigned int hi = f2bfu(tile[j0 + jj * 2 + 1][n]);
    outw[jj] = lo | (hi << 16);
  }
  const int vg = rg / 48;
  const int rl = rg - vg * 48;
  const int ns = rl >> 4, l15 = rl & 15;
  const int kb = k0 >> 5, quad = j0 >> 3;
  *(uint4*)&pdTf[(size_t)(((vg * 3 + ns) * 7 + kb) * 512) + (quad * 16 + l15) * 8] =
      make_uint4(outw[0], outw[1], outw[2], outw[3]);
}

// ---------------------------------------------------------------------------
// Kernel 3 (fused, v4): 2 independent waves/block, 16 batches x 16 vertices
// each. ALL global reads are single coalesced 1KB wave-reads (fragment-major
// operands; lane reads base+lane*8). No staging, no __syncthreads; vpS only
// LDS (6.4KB). XCD chunk swizzle (13792 = 8*1724). launch_bounds(128,8).
// Phase 1: acc[3] = pf @ pdT (+vt) -> vpS (wave-private).
// Phase 2: T^T = mfma(Abff_frag, wf); apply from vpS; single store.
// ---------------------------------------------------------------------------
__global__ __launch_bounds__(128, 8) void fused_mfma(
    const ushort* __restrict__ pfbf, const ushort* __restrict__ pdTf,
    const float* __restrict__ vt, const ushort* __restrict__ wbff,
    const ushort* __restrict__ Abff, float* __restrict__ out_v) {
  __shared__ float vpS[32 * 50];                   // 6400 B, wave-private halves
  const int tid = threadIdx.x;
  const int lane = tid & 63, wv = tid >> 6;        // wv 0..1
  const int l15 = lane & 15, quad = lane >> 4;

  // XCD chunk swizzle: contiguous L-range per XCD
  const int bid = blockIdx.x;                      // grid = 13792 blocks 1-D
  const int L = (bid & 7) * 1724 + (bid >> 3);
  const int bm = (L & 31) * 32 + wv * 16;          // this wave's 16 batches
  const int vg = L >> 5;                           // vertex group 0..430

  // Phase 1: fully-coalesced fragment loads
  const ushort* apf = pfbf + (size_t)((bm >> 4) * 7) * 512 + lane * 8;
  const ushort* bpf = pdTf + (size_t)(vg * 21) * 512 + lane * 8;

  floatx4 acc0 = {0.0f, 0.0f, 0.0f, 0.0f};
  floatx4 acc1 = acc0, acc2 = acc0;
#pragma unroll
  for (int kb = 0; kb < 7; kb++) {
    short8v a  = *(const short8v*)(apf + kb * 512);
    short8v b0 = *(const short8v*)(bpf + (0 * 7 + kb) * 512);
    short8v b1 = *(const short8v*)(bpf + (1 * 7 + kb) * 512);
    short8v b2 = *(const short8v*)(bpf + (2 * 7 + kb) * 512);
    acc0 = __builtin_amdgcn_mfma_f32_16x16x32_bf16(a, b0, acc0, 0, 0, 0);
    acc1 = __builtin_amdgcn_mfma_f32_16x16x32_bf16(a, b1, acc1, 0, 0, 0);
    acc2 = __builtin_amdgcn_mfma_f32_16x16x32_bf16(a, b2, acc2, 0, 0, 0);
  }

  // vt epilogue for this lane's three output columns
  const int gn0 = vg * 48 + l15;
  float vt0 = (gn0      < N3) ? vt[gn0]      : 0.0f;
  float vt1 = (gn0 + 16 < N3) ? vt[gn0 + 16] : 0.0f;
  float vt2 = (gn0 + 32 < N3) ? vt[gn0 + 32] : 0.0f;

  float* myvp = &vpS[wv * 16 * 50];
#pragma unroll
  for (int r = 0; r < 4; r++) {
    int row = quad * 4 + r;
    myvp[row * 50 +      l15] = acc0[r] + vt0;
    myvp[row * 50 + 16 + l15] = acc1[r] + vt1;
    myvp[row * 50 + 32 + l15] = acc2[r] + vt2;
  }
  // Wave-private handoff: this wave's ds_writes complete before its reads.
  __builtin_amdgcn_sched_barrier(0);
  __builtin_amdgcn_s_waitcnt(0xc07f);   // lgkmcnt(0)
  __builtin_amdgcn_sched_barrier(0);

  // Phase 2: blend for this wave's 16 batches (all loads coalesced)
  const short8v wf = *(const short8v*)(wbff + (size_t)vg * 512 + lane * 8);
  const int gv = vg * 16 + l15;
  const bool active = (quad < 3) && (gv < VNUM);
  const size_t vbase = (size_t)gv * 3;
  const ushort* abase = Abff + (size_t)bm * 512 + lane * 8;

  short8v apre[4];
#pragma unroll
  for (int i = 0; i < 4; i++) apre[i] = *(const short8v*)(abase + i * 512);

  const floatx4 zero = {0.0f, 0.0f, 0.0f, 0.0f};
#pragma unroll
  for (int i = 0; i < 16; i++) {
    short8v afrag = apre[i & 3];
    if (i < 12) apre[i & 3] = *(const short8v*)(abase + (i + 4) * 512);
    floatx4 t = zero;
    t = __builtin_amdgcn_mfma_f32_16x16x32_bf16(afrag, wf, t, 0, 0, 0);
    float px = myvp[i * 50 + 3 * l15 + 0];
    float py = myvp[i * 50 + 3 * l15 + 1];
    float pz = myvp[i * 50 + 3 * l15 + 2];
    if (active) {
      out_v[(size_t)(bm + i) * N3 + vbase + quad] =
          t[0] * px + t[1] * py + t[2] * pz + t[3];
    }
  }
}

extern "C" void kernel_launch(void* const* d_in, const int* in_sizes, int n_in,
                              void* d_out, int out_size, void* d_ws, size_t ws_size,
                              hipStream_t stream) {
  const float* body_pose     = (const float*)d_in[0];
  const float* betas         = (const float*)d_in[1];
  const float* global_orient = (const float*)d_in[2];
  const float* v_template    = (const float*)d_in[3];
  const float* shapedirs     = (const float*)d_in[4];
  const float* posedirs      = (const float*)d_in[5];
  const float* J_regressor   = (const float*)d_in[6];
  const float* lbs_weights   = (const float*)d_in[7];

  float* out = (float*)d_out;
  float* out_v  = out + OUT_V;
  float* out_jt = out + OUT_JT;
  float* out_j  = out + OUT_J;
  float* out_rm = out + OUT_RM;

  float* ws = (float*)d_ws;
  float* JvJs = ws + WS_JVJS;
  ushort* Abff = (ushort*)(ws + WS_ABFF);
  ushort* wbff = (ushort*)(ws + WS_WBFF);
  ushort* pfbf = (ushort*)(ws + WS_PFBF);
  ushort* pdTf = (ushort*)(ws + WS_PDTF);

  hipMemsetAsync(JvJs, 0, KJ * 33 * sizeof(float), stream);
  jreg_kernel<<<dim3(KJ, 4), 256, 0, stream>>>(J_regressor, v_template, shapedirs, JvJs);
  transpose_pd<<<dim3(324, 7), 256, 0, stream>>>(posedirs, pdTf, shapedirs,
                                                 lbs_weights, wbff);
  batch_prep<<<BATCH, 64, 0, stream>>>(body_pose, betas, global_orient, JvJs,
                                       out_jt, out_j, out_rm, pfbf, Abff);
  fused_mfma<<<13792, 128, 0, stream>>>(pfbf, pdTf, v_template, wbff, Abff, out_v);
}

// Round 8
// 198.340 us; speedup vs baseline: 1.1404x; 1.0079x over previous
//
#include <hip/hip_runtime.h>
#include <hip/hip_bf16.h>

#define VNUM 6890
#define KJ 24
#define NBETA 10
#define NPOSE 207
#define KPAD 224        // NPOSE padded to 7*32; cols 207..216 carry betas
#define BATCH 1024
#define N3 20670        // VNUM*3
#define NVG 431         // vertex groups of 16
#define NROWF 20688     // NVG*48 rows in pdTf

// d_out element offsets (f32 elements)
#define OUT_V  0
#define OUT_JT 21166080
#define OUT_J  21239808
#define OUT_RM 21313536

// ws offsets (float units), all 16B-aligned
#define WS_JVJS 0                 // 792 floats
#define WS_ABFF 792               // ushort[1024*512]   = 262144 f -> ends 262936
#define WS_WBFF 262936            // ushort[432*512]    = 110592 f -> ends 373528
#define WS_PFBF 373528            // ushort[64*7*512]   = 114688 f -> ends 488216
#define WS_PDTF 488216            // ushort[431*21*512] = 2317056 f -> ends 2805272

typedef unsigned short ushort;
typedef __attribute__((ext_vector_type(8))) short short8v;
typedef __attribute__((ext_vector_type(4))) float floatx4;

__device__ __forceinline__ ushort f2bfu(float x) {
  __hip_bfloat16 h = __float2bfloat16(x);
  union { __hip_bfloat16 h; ushort u; } cv; cv.h = h; return cv.u;
}

// ---------------------------------------------------------------------------
// Kernel 0: JvJs accumulation, split over 4 V-chunks, atomicAdd combine.
// ---------------------------------------------------------------------------
__global__ __launch_bounds__(256) void jreg_kernel(
    const float* __restrict__ Jr, const float* __restrict__ vt,
    const float* __restrict__ sd, float* __restrict__ JvJs) {
  const int j = blockIdx.x;
  const int chunk = blockIdx.y;
  const int t = threadIdx.x;
  const int lane = t & 63, wid = t >> 6;
  const int vbeg = chunk * 1723;
  const int vend = (vbeg + 1723 < VNUM) ? vbeg + 1723 : VNUM;
  __shared__ float red[4][33];
  float acc[33];
#pragma unroll
  for (int q = 0; q < 33; q++) acc[q] = 0.0f;
  for (int v = vbeg + t; v < vend; v += 256) {
    float r = Jr[j * VNUM + v];
    const float* vtp = vt + v * 3;
    const float* sdp = sd + v * 30;
    acc[0] += r * vtp[0];
    acc[1] += r * vtp[1];
    acc[2] += r * vtp[2];
#pragma unroll
    for (int q = 0; q < 30; q++) acc[3 + q] += r * sdp[q];
  }
#pragma unroll
  for (int q = 0; q < 33; q++) {
    float x = acc[q];
    for (int off = 32; off > 0; off >>= 1) x += __shfl_down(x, off, 64);
    if (lane == 0) red[wid][q] = x;
  }
  __syncthreads();
  if (t < 33)
    atomicAdd(&JvJs[j * 33 + t], red[0][t] + red[1][t] + red[2][t] + red[3][t]);
}

// ---------------------------------------------------------------------------
// Kernel 1: per-batch: rodrigues, joints_t, chain; writes FRAGMENT-MAJOR
// pfbf[(b>>4)*7+kb][lane*8] (lane=quad*16+(b&15)) and Abff[b][lane*8]
// (lane=quad*16+n, k=quad*8+j, n=12..15 zero).
// pose-feature row: [0..206]=pf, [207..216]=betas, [217..223]=0.
// ---------------------------------------------------------------------------
__global__ __launch_bounds__(64) void batch_prep(
    const float* __restrict__ body_pose, const float* __restrict__ betas,
    const float* __restrict__ global_orient, const float* __restrict__ JvJs,
    float* __restrict__ out_jt, float* __restrict__ out_j, float* __restrict__ out_rm,
    ushort* __restrict__ pfbf, ushort* __restrict__ Abff) {
  const int b = blockIdx.x;
  const int t = threadIdx.x;
  __shared__ float R[24][9];
  __shared__ float jt[24][3];
  __shared__ float chR[24][9];
  __shared__ float cht[24][3];

  if (t < 24) {
    float ax, ay, az;
    if (t == 0) {
      ax = global_orient[b * 3 + 0];
      ay = global_orient[b * 3 + 1];
      az = global_orient[b * 3 + 2];
    } else {
      const float* p = body_pose + (size_t)b * 69 + (t - 1) * 3;
      ax = p[0]; ay = p[1]; az = p[2];
    }
    float px = ax + 1e-8f, py = ay + 1e-8f, pz = az + 1e-8f;
    float angle = sqrtf(px * px + py * py + pz * pz);
    float inv = 1.0f / angle;
    float rx = ax * inv, ry = ay * inv, rz = az * inv;
    float s = sinf(angle), c = cosf(angle);
    float cc = 1.0f - c;
    float m[9];
    m[0] = 1.0f - cc * (ry * ry + rz * rz);
    m[1] = -s * rz + cc * rx * ry;
    m[2] =  s * ry + cc * rx * rz;
    m[3] =  s * rz + cc * rx * ry;
    m[4] = 1.0f - cc * (rx * rx + rz * rz);
    m[5] = -s * rx + cc * ry * rz;
    m[6] = -s * ry + cc * rx * rz;
    m[7] =  s * rx + cc * ry * rz;
    m[8] = 1.0f - cc * (rx * rx + ry * ry);
#pragma unroll
    for (int e = 0; e < 9; e++) {
      R[t][e] = m[e];
      out_rm[(size_t)b * 216 + t * 9 + e] = m[e];
    }
  }
  for (int idx = t; idx < 72; idx += 64) {
    int j = idx / 3, c = idx % 3;
    const float* JJ = JvJs + j * 33;
    float s = JJ[c];
    const float* be = betas + (size_t)b * NBETA;
#pragma unroll
    for (int l = 0; l < NBETA; l++) s += be[l] * JJ[3 + c * 10 + l];
    jt[j][c] = s;
    out_jt[(size_t)b * 72 + idx] = s;
  }
  __syncthreads();
  // pose-feature fragment write: k = mI, dst lane = quad*16 + (b&15)
  for (int mI = t; mI < KPAD; mI += 64) {
    float val = 0.0f;
    if (mI < NPOSE) {
      int k = 1 + mI / 9, e = mI % 9;
      val = R[k][e] - ((e == 0 || e == 4 || e == 8) ? 1.0f : 0.0f);
    } else if (mI < NPOSE + NBETA) {
      val = betas[(size_t)b * NBETA + (mI - NPOSE)];
    }
    int kb = mI >> 5, quad = (mI >> 3) & 3, j = mI & 7;
    pfbf[(size_t)(((b >> 4) * 7 + kb) * 512) + (quad * 16 + (b & 15)) * 8 + j] =
        f2bfu(val);
  }
  if (t == 0) {
    const int par[24] = {-1, 0, 0, 0, 1, 2, 3, 4, 5, 6, 7, 8, 9, 9, 9, 12, 13, 14, 16, 17, 18, 19, 20, 21};
#pragma unroll
    for (int e = 0; e < 9; e++) chR[0][e] = R[0][e];
    cht[0][0] = jt[0][0]; cht[0][1] = jt[0][1]; cht[0][2] = jt[0][2];
    for (int k = 1; k < 24; k++) {
      int p = par[k];
      float rel0 = jt[k][0] - jt[p][0];
      float rel1 = jt[k][1] - jt[p][1];
      float rel2 = jt[k][2] - jt[p][2];
#pragma unroll
      for (int i = 0; i < 3; i++) {
        float a0 = chR[p][i * 3 + 0], a1 = chR[p][i * 3 + 1], a2 = chR[p][i * 3 + 2];
        chR[k][i * 3 + 0] = a0 * R[k][0] + a1 * R[k][3] + a2 * R[k][6];
        chR[k][i * 3 + 1] = a0 * R[k][1] + a1 * R[k][4] + a2 * R[k][7];
        chR[k][i * 3 + 2] = a0 * R[k][2] + a1 * R[k][5] + a2 * R[k][8];
        cht[k][i] = a0 * rel0 + a1 * rel1 + a2 * rel2 + cht[p][i];
      }
    }
  }
  __syncthreads();
  if (t < 24) {
    int k = t;
#pragma unroll
    for (int i = 0; i < 3; i++) out_j[(size_t)b * 72 + k * 3 + i] = cht[k][i];
  }
  // Abff[b*512 + e]: e = (quad*16+n)*8+j, k = quad*8+j; n>=12 or k>=24 -> 0
  for (int e = t; e < 512; e += 64) {
    int quad = e >> 7, n = (e >> 3) & 15, j = e & 7;
    int k = quad * 8 + j;
    float val = 0.0f;
    if (n < 12 && k < 24) {
      int i = n >> 2, jj = n & 3;
      if (jj < 3) {
        val = chR[k][i * 3 + jj];
      } else {
        val = cht[k][i] - (chR[k][i * 3 + 0] * jt[k][0] +
                           chR[k][i * 3 + 1] * jt[k][1] +
                           chR[k][i * 3 + 2] * jt[k][2]);
      }
    }
    Abff[(size_t)b * 512 + e] = f2bfu(val);
  }
}

// ---------------------------------------------------------------------------
// Kernel 2: fragment-major pdTf (k<207 from pd^T, 207..216 from sd, else 0);
// 864 blocks also convert lbs_weights -> fragment-major wbff[vg][lane*8].
// ---------------------------------------------------------------------------
__global__ __launch_bounds__(256) void transpose_pd(
    const float* __restrict__ pd, ushort* __restrict__ pdTf,
    const float* __restrict__ sd,
    const float* __restrict__ w, ushort* __restrict__ wbff) {
  {
    int lb = blockIdx.y * 324 + blockIdx.x;
    if (lb < 864) {                           // 432*512/256 = 864
      int i = lb * 256 + threadIdx.x;
      int vg = i >> 9, e = i & 511;
      int quad = e >> 7, l15 = (e >> 3) & 15, j = e & 7;
      int v = vg * 16 + l15, k = quad * 8 + j;
      float x = (v < VNUM && k < 24) ? w[v * 24 + k] : 0.0f;
      wbff[i] = f2bfu(x);
    }
  }
  __shared__ float tile[32][65];
  const int t = threadIdx.x;
  const int n0 = blockIdx.x * 64;
  const int k0 = blockIdx.y * 32;
  const int c = t & 63;
  for (int r = t >> 6; r < 32; r += 4) {
    int k = k0 + r, n = n0 + c;
    float x = 0.0f;
    if (n < N3) {
      if (k < NPOSE) x = pd[(size_t)k * N3 + n];
      else if (k < NPOSE + NBETA) x = sd[(size_t)n * 10 + (k - NPOSE)];
    }
    tile[r][c] = x;
  }
  __syncthreads();
  const int n = t >> 2;               // local row 0..63
  const int j0 = (t & 3) * 8;         // k offset within 32
  const int rg = n0 + n;              // global row
  if (rg >= NROWF) return;
  unsigned int outw[4];
#pragma unroll
  for (int jj = 0; jj < 4; jj++) {
    unsigned int lo = f2bfu(tile[j0 + jj * 2][n]);
    unsigned int hi = f2bfu(tile[j0 + jj * 2 + 1][n]);
    outw[jj] = lo | (hi << 16);
  }
  const int vg = rg / 48;
  const int rl = rg - vg * 48;
  const int ns = rl >> 4, l15 = rl & 15;
  const int kb = k0 >> 5, quad = j0 >> 3;
  *(uint4*)&pdTf[(size_t)(((vg * 3 + ns) * 7 + kb) * 512) + (quad * 16 + l15) * 8] =
      make_uint4(outw[0], outw[1], outw[2], outw[3]);
}

// ---------------------------------------------------------------------------
// Kernel 3 (fused, v5): structure of v4 + exposed-latency fixes:
// - launch_bounds(128,6): 85-VGPR budget (was 64) so phase-1's 28 loads can
//   stay in flight instead of small serialized batches (R7: VGPR=32 proved
//   the allocator was squeezed).
// - wf/vt loads hoisted to kernel start (off the phase-2 critical path).
// - p-ring: LDS float3 reads prefetched 4 iters ahead (static slots),
//   mirroring the proven apre ring; kills ~120cy/iter exposed DS latency.
// - pointer-increment store addressing.
// ---------------------------------------------------------------------------
__global__ __launch_bounds__(128, 6) void fused_mfma(
    const ushort* __restrict__ pfbf, const ushort* __restrict__ pdTf,
    const float* __restrict__ vt, const ushort* __restrict__ wbff,
    const ushort* __restrict__ Abff, float* __restrict__ out_v) {
  __shared__ float vpS[32 * 50];                   // 6400 B, wave-private halves
  const int tid = threadIdx.x;
  const int lane = tid & 63, wv = tid >> 6;        // wv 0..1
  const int l15 = lane & 15, quad = lane >> 4;

  // XCD chunk swizzle: contiguous L-range per XCD
  const int bid = blockIdx.x;                      // grid = 13792 blocks 1-D
  const int L = (bid & 7) * 1724 + (bid >> 3);
  const int bm = (L & 31) * 32 + wv * 16;          // this wave's 16 batches
  const int vg = L >> 5;                           // vertex group 0..430

  // Issue phase-2 invariants FIRST (latency hides under phase 1)
  const short8v wf = *(const short8v*)(wbff + (size_t)vg * 512 + lane * 8);
  const int gn0 = vg * 48 + l15;
  float vt0 = (gn0      < N3) ? vt[gn0]      : 0.0f;
  float vt1 = (gn0 + 16 < N3) ? vt[gn0 + 16] : 0.0f;
  float vt2 = (gn0 + 32 < N3) ? vt[gn0 + 32] : 0.0f;

  // Phase 1: fully-coalesced fragment loads
  const ushort* apf = pfbf + (size_t)((bm >> 4) * 7) * 512 + lane * 8;
  const ushort* bpf = pdTf + (size_t)(vg * 21) * 512 + lane * 8;

  floatx4 acc0 = {0.0f, 0.0f, 0.0f, 0.0f};
  floatx4 acc1 = acc0, acc2 = acc0;
#pragma unroll
  for (int kb = 0; kb < 7; kb++) {
    short8v a  = *(const short8v*)(apf + kb * 512);
    short8v b0 = *(const short8v*)(bpf + (0 * 7 + kb) * 512);
    short8v b1 = *(const short8v*)(bpf + (1 * 7 + kb) * 512);
    short8v b2 = *(const short8v*)(bpf + (2 * 7 + kb) * 512);
    acc0 = __builtin_amdgcn_mfma_f32_16x16x32_bf16(a, b0, acc0, 0, 0, 0);
    acc1 = __builtin_amdgcn_mfma_f32_16x16x32_bf16(a, b1, acc1, 0, 0, 0);
    acc2 = __builtin_amdgcn_mfma_f32_16x16x32_bf16(a, b2, acc2, 0, 0, 0);
  }

  float* myvp = &vpS[wv * 16 * 50];
#pragma unroll
  for (int r = 0; r < 4; r++) {
    int row = quad * 4 + r;
    myvp[row * 50 +      l15] = acc0[r] + vt0;
    myvp[row * 50 + 16 + l15] = acc1[r] + vt1;
    myvp[row * 50 + 32 + l15] = acc2[r] + vt2;
  }
  // Wave-private handoff: this wave's ds_writes complete before its reads.
  __builtin_amdgcn_sched_barrier(0);
  __builtin_amdgcn_s_waitcnt(0xc07f);   // lgkmcnt(0)
  __builtin_amdgcn_sched_barrier(0);

  // Phase 2: blend for this wave's 16 batches
  const int gv = vg * 16 + l15;
  const bool active = (quad < 3) && (gv < VNUM);
  const ushort* abase = Abff + (size_t)bm * 512 + lane * 8;
  float* outp = out_v + (size_t)bm * N3 + (size_t)gv * 3 + quad;
  const float* pbase = myvp + 3 * l15;

  // 4-deep prefetch rings (static slots via full unroll)
  short8v apre[4];
  float ppx[4], ppy[4], ppz[4];
#pragma unroll
  for (int i = 0; i < 4; i++) {
    apre[i] = *(const short8v*)(abase + i * 512);
    ppx[i] = pbase[i * 50 + 0];
    ppy[i] = pbase[i * 50 + 1];
    ppz[i] = pbase[i * 50 + 2];
  }

  const floatx4 zero = {0.0f, 0.0f, 0.0f, 0.0f};
#pragma unroll
  for (int i = 0; i < 16; i++) {
    const int slot = i & 3;
    short8v afrag = apre[slot];
    float px = ppx[slot], py = ppy[slot], pz = ppz[slot];
    if (i < 12) {
      apre[slot] = *(const short8v*)(abase + (i + 4) * 512);
      ppx[slot] = pbase[(i + 4) * 50 + 0];
      ppy[slot] = pbase[(i + 4) * 50 + 1];
      ppz[slot] = pbase[(i + 4) * 50 + 2];
    }
    floatx4 t = zero;
    t = __builtin_amdgcn_mfma_f32_16x16x32_bf16(afrag, wf, t, 0, 0, 0);
    if (active) {
      *outp = t[0] * px + t[1] * py + t[2] * pz + t[3];
    }
    outp += N3;
  }
}

extern "C" void kernel_launch(void* const* d_in, const int* in_sizes, int n_in,
                              void* d_out, int out_size, void* d_ws, size_t ws_size,
                              hipStream_t stream) {
  const float* body_pose     = (const float*)d_in[0];
  const float* betas         = (const float*)d_in[1];
  const float* global_orient = (const float*)d_in[2];
  const float* v_template    = (const float*)d_in[3];
  const float* shapedirs     = (const float*)d_in[4];
  const float* posedirs      = (const float*)d_in[5];
  const float* J_regressor   = (const float*)d_in[6];
  const float* lbs_weights   = (const float*)d_in[7];

  float* out = (float*)d_out;
  float* out_v  = out + OUT_V;
  float* out_jt = out + OUT_JT;
  float* out_j  = out + OUT_J;
  float* out_rm = out + OUT_RM;

  float* ws = (float*)d_ws;
  float* JvJs = ws + WS_JVJS;
  ushort* Abff = (ushort*)(ws + WS_ABFF);
  ushort* wbff = (ushort*)(ws + WS_WBFF);
  ushort* pfbf = (ushort*)(ws + WS_PFBF);
  ushort* pdTf = (ushort*)(ws + WS_PDTF);

  hipMemsetAsync(JvJs, 0, KJ * 33 * sizeof(float), stream);
  jreg_kernel<<<dim3(KJ, 4), 256, 0, stream>>>(J_regressor, v_template, shapedirs, JvJs);
  transpose_pd<<<dim3(324, 7), 256, 0, stream>>>(posedirs, pdTf, shapedirs,
                                                 lbs_weights, wbff);
  batch_prep<<<BATCH, 64, 0, stream>>>(body_pose, betas, global_orient, JvJs,
                                       out_jt, out_j, out_rm, pfbf, Abff);
  fused_mfma<<<13792, 128, 0, stream>>>(pfbf, pdTf, v_template, wbff, Abff, out_v);
}

// Round 9
// 197.103 us; speedup vs baseline: 1.1475x; 1.0063x over previous
//
#include <hip/hip_runtime.h>
#include <hip/hip_bf16.h>

#define VNUM 6890
#define KJ 24
#define NBETA 10
#define NPOSE 207
#define KPAD 224        // NPOSE padded to 7*32; cols 207..216 carry betas
#define BATCH 1024
#define N3 20670        // VNUM*3
#define NVG 431         // vertex groups of 16
#define NROWF 20688     // NVG*48 rows in pdTf

// d_out element offsets (f32 elements)
#define OUT_V  0
#define OUT_JT 21166080
#define OUT_J  21239808
#define OUT_RM 21313536

// ws offsets (float units), all 16B-aligned
#define WS_JVJS 0                 // 792 floats
#define WS_ABFF 792               // ushort[1024*512]   = 262144 f -> ends 262936
#define WS_WBFF 262936            // ushort[432*512]    = 110592 f -> ends 373528
#define WS_PFBF 373528            // ushort[64*7*512]   = 114688 f -> ends 488216
#define WS_PDTF 488216            // ushort[431*21*512] = 2317056 f -> ends 2805272

typedef unsigned short ushort;
typedef __attribute__((ext_vector_type(8))) short short8v;
typedef __attribute__((ext_vector_type(4))) float floatx4;

__device__ __forceinline__ ushort f2bfu(float x) {
  __hip_bfloat16 h = __float2bfloat16(x);
  union { __hip_bfloat16 h; ushort u; } cv; cv.h = h; return cv.u;
}

// ---------------------------------------------------------------------------
// Kernel 0: JvJs accumulation, split over 4 V-chunks, atomicAdd combine.
// ---------------------------------------------------------------------------
__global__ __launch_bounds__(256) void jreg_kernel(
    const float* __restrict__ Jr, const float* __restrict__ vt,
    const float* __restrict__ sd, float* __restrict__ JvJs) {
  const int j = blockIdx.x;
  const int chunk = blockIdx.y;
  const int t = threadIdx.x;
  const int lane = t & 63, wid = t >> 6;
  const int vbeg = chunk * 1723;
  const int vend = (vbeg + 1723 < VNUM) ? vbeg + 1723 : VNUM;
  __shared__ float red[4][33];
  float acc[33];
#pragma unroll
  for (int q = 0; q < 33; q++) acc[q] = 0.0f;
  for (int v = vbeg + t; v < vend; v += 256) {
    float r = Jr[j * VNUM + v];
    const float* vtp = vt + v * 3;
    const float* sdp = sd + v * 30;
    acc[0] += r * vtp[0];
    acc[1] += r * vtp[1];
    acc[2] += r * vtp[2];
#pragma unroll
    for (int q = 0; q < 30; q++) acc[3 + q] += r * sdp[q];
  }
#pragma unroll
  for (int q = 0; q < 33; q++) {
    float x = acc[q];
    for (int off = 32; off > 0; off >>= 1) x += __shfl_down(x, off, 64);
    if (lane == 0) red[wid][q] = x;
  }
  __syncthreads();
  if (t < 33)
    atomicAdd(&JvJs[j * 33 + t], red[0][t] + red[1][t] + red[2][t] + red[3][t]);
}

// ---------------------------------------------------------------------------
// Kernel 1: per-batch: rodrigues, joints_t, chain; writes FRAGMENT-MAJOR
// pfbf[(b>>4)*7+kb][lane*8] (lane=quad*16+(b&15)) and Abff[b][lane*8]
// (lane=quad*16+n, k=quad*8+j, n=12..15 zero).
// pose-feature row: [0..206]=pf, [207..216]=betas, [217..223]=0.
// ---------------------------------------------------------------------------
__global__ __launch_bounds__(64) void batch_prep(
    const float* __restrict__ body_pose, const float* __restrict__ betas,
    const float* __restrict__ global_orient, const float* __restrict__ JvJs,
    float* __restrict__ out_jt, float* __restrict__ out_j, float* __restrict__ out_rm,
    ushort* __restrict__ pfbf, ushort* __restrict__ Abff) {
  const int b = blockIdx.x;
  const int t = threadIdx.x;
  __shared__ float R[24][9];
  __shared__ float jt[24][3];
  __shared__ float chR[24][9];
  __shared__ float cht[24][3];

  if (t < 24) {
    float ax, ay, az;
    if (t == 0) {
      ax = global_orient[b * 3 + 0];
      ay = global_orient[b * 3 + 1];
      az = global_orient[b * 3 + 2];
    } else {
      const float* p = body_pose + (size_t)b * 69 + (t - 1) * 3;
      ax = p[0]; ay = p[1]; az = p[2];
    }
    float px = ax + 1e-8f, py = ay + 1e-8f, pz = az + 1e-8f;
    float angle = sqrtf(px * px + py * py + pz * pz);
    float inv = 1.0f / angle;
    float rx = ax * inv, ry = ay * inv, rz = az * inv;
    float s = sinf(angle), c = cosf(angle);
    float cc = 1.0f - c;
    float m[9];
    m[0] = 1.0f - cc * (ry * ry + rz * rz);
    m[1] = -s * rz + cc * rx * ry;
    m[2] =  s * ry + cc * rx * rz;
    m[3] =  s * rz + cc * rx * ry;
    m[4] = 1.0f - cc * (rx * rx + rz * rz);
    m[5] = -s * rx + cc * ry * rz;
    m[6] = -s * ry + cc * rx * rz;
    m[7] =  s * rx + cc * ry * rz;
    m[8] = 1.0f - cc * (rx * rx + ry * ry);
#pragma unroll
    for (int e = 0; e < 9; e++) {
      R[t][e] = m[e];
      out_rm[(size_t)b * 216 + t * 9 + e] = m[e];
    }
  }
  for (int idx = t; idx < 72; idx += 64) {
    int j = idx / 3, c = idx % 3;
    const float* JJ = JvJs + j * 33;
    float s = JJ[c];
    const float* be = betas + (size_t)b * NBETA;
#pragma unroll
    for (int l = 0; l < NBETA; l++) s += be[l] * JJ[3 + c * 10 + l];
    jt[j][c] = s;
    out_jt[(size_t)b * 72 + idx] = s;
  }
  __syncthreads();
  // pose-feature fragment write: k = mI, dst lane = quad*16 + (b&15)
  for (int mI = t; mI < KPAD; mI += 64) {
    float val = 0.0f;
    if (mI < NPOSE) {
      int k = 1 + mI / 9, e = mI % 9;
      val = R[k][e] - ((e == 0 || e == 4 || e == 8) ? 1.0f : 0.0f);
    } else if (mI < NPOSE + NBETA) {
      val = betas[(size_t)b * NBETA + (mI - NPOSE)];
    }
    int kb = mI >> 5, quad = (mI >> 3) & 3, j = mI & 7;
    pfbf[(size_t)(((b >> 4) * 7 + kb) * 512) + (quad * 16 + (b & 15)) * 8 + j] =
        f2bfu(val);
  }
  if (t == 0) {
    const int par[24] = {-1, 0, 0, 0, 1, 2, 3, 4, 5, 6, 7, 8, 9, 9, 9, 12, 13, 14, 16, 17, 18, 19, 20, 21};
#pragma unroll
    for (int e = 0; e < 9; e++) chR[0][e] = R[0][e];
    cht[0][0] = jt[0][0]; cht[0][1] = jt[0][1]; cht[0][2] = jt[0][2];
    for (int k = 1; k < 24; k++) {
      int p = par[k];
      float rel0 = jt[k][0] - jt[p][0];
      float rel1 = jt[k][1] - jt[p][1];
      float rel2 = jt[k][2] - jt[p][2];
#pragma unroll
      for (int i = 0; i < 3; i++) {
        float a0 = chR[p][i * 3 + 0], a1 = chR[p][i * 3 + 1], a2 = chR[p][i * 3 + 2];
        chR[k][i * 3 + 0] = a0 * R[k][0] + a1 * R[k][3] + a2 * R[k][6];
        chR[k][i * 3 + 1] = a0 * R[k][1] + a1 * R[k][4] + a2 * R[k][7];
        chR[k][i * 3 + 2] = a0 * R[k][2] + a1 * R[k][5] + a2 * R[k][8];
        cht[k][i] = a0 * rel0 + a1 * rel1 + a2 * rel2 + cht[p][i];
      }
    }
  }
  __syncthreads();
  if (t < 24) {
    int k = t;
#pragma unroll
    for (int i = 0; i < 3; i++) out_j[(size_t)b * 72 + k * 3 + i] = cht[k][i];
  }
  // Abff[b*512 + e]: e = (quad*16+n)*8+j, k = quad*8+j; n>=12 or k>=24 -> 0
  for (int e = t; e < 512; e += 64) {
    int quad = e >> 7, n = (e >> 3) & 15, j = e & 7;
    int k = quad * 8 + j;
    float val = 0.0f;
    if (n < 12 && k < 24) {
      int i = n >> 2, jj = n & 3;
      if (jj < 3) {
        val = chR[k][i * 3 + jj];
      } else {
        val = cht[k][i] - (chR[k][i * 3 + 0] * jt[k][0] +
                           chR[k][i * 3 + 1] * jt[k][1] +
                           chR[k][i * 3 + 2] * jt[k][2]);
      }
    }
    Abff[(size_t)b * 512 + e] = f2bfu(val);
  }
}

// ---------------------------------------------------------------------------
// Kernel 2: fragment-major pdTf (k<207 from pd^T, 207..216 from sd, else 0);
// 864 blocks also convert lbs_weights -> fragment-major wbff[vg][lane*8].
// ---------------------------------------------------------------------------
__global__ __launch_bounds__(256) void transpose_pd(
    const float* __restrict__ pd, ushort* __restrict__ pdTf,
    const float* __restrict__ sd,
    const float* __restrict__ w, ushort* __restrict__ wbff) {
  {
    int lb = blockIdx.y * 324 + blockIdx.x;
    if (lb < 864) {                           // 432*512/256 = 864
      int i = lb * 256 + threadIdx.x;
      int vg = i >> 9, e = i & 511;
      int quad = e >> 7, l15 = (e >> 3) & 15, j = e & 7;
      int v = vg * 16 + l15, k = quad * 8 + j;
      float x = (v < VNUM && k < 24) ? w[v * 24 + k] : 0.0f;
      wbff[i] = f2bfu(x);
    }
  }
  __shared__ float tile[32][65];
  const int t = threadIdx.x;
  const int n0 = blockIdx.x * 64;
  const int k0 = blockIdx.y * 32;
  const int c = t & 63;
  for (int r = t >> 6; r < 32; r += 4) {
    int k = k0 + r, n = n0 + c;
    float x = 0.0f;
    if (n < N3) {
      if (k < NPOSE) x = pd[(size_t)k * N3 + n];
      else if (k < NPOSE + NBETA) x = sd[(size_t)n * 10 + (k - NPOSE)];
    }
    tile[r][c] = x;
  }
  __syncthreads();
  const int n = t >> 2;               // local row 0..63
  const int j0 = (t & 3) * 8;         // k offset within 32
  const int rg = n0 + n;              // global row
  if (rg >= NROWF) return;
  unsigned int outw[4];
#pragma unroll
  for (int jj = 0; jj < 4; jj++) {
    unsigned int lo = f2bfu(tile[j0 + jj * 2][n]);
    unsigned int hi = f2bfu(tile[j0 + jj * 2 + 1][n]);
    outw[jj] = lo | (hi << 16);
  }
  const int vg = rg / 48;
  const int rl = rg - vg * 48;
  const int ns = rl >> 4, l15 = rl & 15;
  const int kb = k0 >> 5, quad = j0 >> 3;
  *(uint4*)&pdTf[(size_t)(((vg * 3 + ns) * 7 + kb) * 512) + (quad * 16 + l15) * 8] =
      make_uint4(outw[0], outw[1], outw[2], outw[3]);
}

// ---------------------------------------------------------------------------
// Kernel 3 (fused, v6): block = 4 waves, SAME 32 batches, 4 DIFFERENT vgs.
// Memory-pipe-bound fix (R8 falsified latency theory): cut L2/TA traffic
// per work-unit ~2x via reuse:
//  - wave tile 32 batches x 16 verts: 21 bpf loads amortized over 2 bgroups
//  - Abff (32 frags, 32 KB) staged ONCE per block into LDS (T14 pattern:
//    loads issued at kernel start, ds_write after phase 1, one barrier) ->
//    phase-2 A-operands come from LDS, not 4x-redundant VMEM.
// Per-block VMEM read ~177 KB for 4x old per-wave work (was ~45 KB/unit).
// LDS: AbS 32K + vpS 25.6K = 58K -> 2 blocks/CU (8 waves).
// Grid 3456 = 8*432: bijective XCD chunking, bt fastest (pdTf quad L2-hot).
// ---------------------------------------------------------------------------
__global__ __launch_bounds__(256, 2) void fused_mfma(
    const ushort* __restrict__ pfbf, const ushort* __restrict__ pdTf,
    const float* __restrict__ vt, const ushort* __restrict__ wbff,
    const ushort* __restrict__ Abff, float* __restrict__ out_v) {
  __shared__ __align__(16) ushort AbS[32 * 512];   // 32 KB, block-shared
  __shared__ float vpS[4][32 * 50];                // 25.6 KB, wave-private
  const int tid = threadIdx.x;
  const int lane = tid & 63, wv = tid >> 6;        // 4 waves
  const int l15 = lane & 15, quad = lane >> 4;

  const int bid = blockIdx.x;                      // 3456 = 8*432
  const int L = (bid & 7) * 432 + (bid >> 3);
  const int bt = L & 31;                           // batch tile (fastest)
  const int q  = L >> 5;                           // vg-quad 0..107
  const int bm = bt * 32;                          // block's 32 batches
  const int vg = q * 4 + wv;
  const int vgc = (vg < NVG) ? vg : (NVG - 1);

  // T14 issue-early: this wave's 8 AbS fragments (write-late after phase 1)
  short8v ab[8];
  {
    const ushort* asrc = Abff + (size_t)(bm + wv * 8) * 512 + lane * 8;
#pragma unroll
    for (int j = 0; j < 8; j++) ab[j] = *(const short8v*)(asrc + j * 512);
  }

  // phase-2 invariants issued early (hide under phase 1)
  const short8v wf = *(const short8v*)(wbff + (size_t)vgc * 512 + lane * 8);
  const int gn0 = vgc * 48 + l15;
  float vt0 = (gn0      < N3) ? vt[gn0]      : 0.0f;
  float vt1 = (gn0 + 16 < N3) ? vt[gn0 + 16] : 0.0f;
  float vt2 = (gn0 + 32 < N3) ? vt[gn0 + 32] : 0.0f;

  // Phase 1: 2 batch-groups x own vg (48 cols); bpf shared across bgroups
  const ushort* apf0 = pfbf + (size_t)((bm >> 4) * 7) * 512 + lane * 8;
  const ushort* apf1 = apf0 + 7 * 512;
  const ushort* bpf  = pdTf + (size_t)(vgc * 21) * 512 + lane * 8;

  const floatx4 zero = {0.0f, 0.0f, 0.0f, 0.0f};
  floatx4 acc[2][3];
#pragma unroll
  for (int bg = 0; bg < 2; bg++)
#pragma unroll
    for (int ns = 0; ns < 3; ns++) acc[bg][ns] = zero;

#pragma unroll
  for (int kb = 0; kb < 7; kb++) {
    short8v a0 = *(const short8v*)(apf0 + kb * 512);
    short8v a1 = *(const short8v*)(apf1 + kb * 512);
    short8v b0 = *(const short8v*)(bpf + (0 * 7 + kb) * 512);
    short8v b1 = *(const short8v*)(bpf + (1 * 7 + kb) * 512);
    short8v b2 = *(const short8v*)(bpf + (2 * 7 + kb) * 512);
    acc[0][0] = __builtin_amdgcn_mfma_f32_16x16x32_bf16(a0, b0, acc[0][0], 0, 0, 0);
    acc[0][1] = __builtin_amdgcn_mfma_f32_16x16x32_bf16(a0, b1, acc[0][1], 0, 0, 0);
    acc[0][2] = __builtin_amdgcn_mfma_f32_16x16x32_bf16(a0, b2, acc[0][2], 0, 0, 0);
    acc[1][0] = __builtin_amdgcn_mfma_f32_16x16x32_bf16(a1, b0, acc[1][0], 0, 0, 0);
    acc[1][1] = __builtin_amdgcn_mfma_f32_16x16x32_bf16(a1, b1, acc[1][1], 0, 0, 0);
    acc[1][2] = __builtin_amdgcn_mfma_f32_16x16x32_bf16(a1, b2, acc[1][2], 0, 0, 0);
  }

  float* myvp = vpS[wv];
#pragma unroll
  for (int bg = 0; bg < 2; bg++) {
#pragma unroll
    for (int r = 0; r < 4; r++) {
      int row = bg * 16 + quad * 4 + r;
      myvp[row * 50 +      l15] = acc[bg][0][r] + vt0;
      myvp[row * 50 + 16 + l15] = acc[bg][1][r] + vt1;
      myvp[row * 50 + 32 + l15] = acc[bg][2][r] + vt2;
    }
  }

  // write-late: AbS staging (loads were issued at kernel start)
  {
    ushort* adst = AbS + (size_t)(wv * 8) * 512 + lane * 8;
#pragma unroll
    for (int j = 0; j < 8; j++) *(short8v*)(adst + j * 512) = ab[j];
  }
  __syncthreads();   // covers AbS (cross-wave) and vpS (own-wave)

  // Phase 2: 32 batches for this wave's vg; A-fragments from LDS
  const int gv = vgc * 16 + l15;
  const bool active = (quad < 3) && (vg < NVG) && (gv < VNUM);
  float* outp = out_v + (size_t)bm * N3 + (size_t)gv * 3 + quad;
  const float* pbase = myvp + 3 * l15;

#pragma unroll
  for (int i = 0; i < 32; i++) {
    short8v afrag = *(const short8v*)&AbS[i * 512 + lane * 8];
    floatx4 t = __builtin_amdgcn_mfma_f32_16x16x32_bf16(afrag, wf, zero, 0, 0, 0);
    float px = pbase[i * 50 + 0];
    float py = pbase[i * 50 + 1];
    float pz = pbase[i * 50 + 2];
    if (active) {
      *outp = t[0] * px + t[1] * py + t[2] * pz + t[3];
    }
    outp += N3;
  }
}

extern "C" void kernel_launch(void* const* d_in, const int* in_sizes, int n_in,
                              void* d_out, int out_size, void* d_ws, size_t ws_size,
                              hipStream_t stream) {
  const float* body_pose     = (const float*)d_in[0];
  const float* betas         = (const float*)d_in[1];
  const float* global_orient = (const float*)d_in[2];
  const float* v_template    = (const float*)d_in[3];
  const float* shapedirs     = (const float*)d_in[4];
  const float* posedirs      = (const float*)d_in[5];
  const float* J_regressor   = (const float*)d_in[6];
  const float* lbs_weights   = (const float*)d_in[7];

  float* out = (float*)d_out;
  float* out_v  = out + OUT_V;
  float* out_jt = out + OUT_JT;
  float* out_j  = out + OUT_J;
  float* out_rm = out + OUT_RM;

  float* ws = (float*)d_ws;
  float* JvJs = ws + WS_JVJS;
  ushort* Abff = (ushort*)(ws + WS_ABFF);
  ushort* wbff = (ushort*)(ws + WS_WBFF);
  ushort* pfbf = (ushort*)(ws + WS_PFBF);
  ushort* pdTf = (ushort*)(ws + WS_PDTF);

  hipMemsetAsync(JvJs, 0, KJ * 33 * sizeof(float), stream);
  jreg_kernel<<<dim3(KJ, 4), 256, 0, stream>>>(J_regressor, v_template, shapedirs, JvJs);
  transpose_pd<<<dim3(324, 7), 256, 0, stream>>>(posedirs, pdTf, shapedirs,
                                                 lbs_weights, wbff);
  batch_prep<<<BATCH, 64, 0, stream>>>(body_pose, betas, global_orient, JvJs,
                                       out_jt, out_j, out_rm, pfbf, Abff);
  fused_mfma<<<3456, 256, 0, stream>>>(pfbf, pdTf, v_template, wbff, Abff, out_v);
}

// Round 10
// 182.252 us; speedup vs baseline: 1.2411x; 1.0815x over previous
//
#include <hip/hip_runtime.h>
#include <hip/hip_bf16.h>

#define VNUM 6890
#define KJ 24
#define NBETA 10
#define NPOSE 207
#define KPAD 224        // NPOSE padded to 7*32; cols 207..216 carry betas
#define BATCH 1024
#define N3 20670        // VNUM*3
#define NVG 431         // vertex groups of 16
#define NROWF 20688     // NVG*48 rows in pdTf

// d_out element offsets (f32 elements)
#define OUT_V  0
#define OUT_JT 21166080
#define OUT_J  21239808
#define OUT_RM 21313536

// ws offsets (float units), all 16B-aligned
#define WS_JVJS 0                 // 792 floats
#define WS_ABFF 792               // ushort[1024*512]   = 262144 f -> ends 262936
#define WS_WBFF 262936            // ushort[432*512]    = 110592 f -> ends 373528
#define WS_PFBF 373528            // ushort[64*7*512]   = 114688 f -> ends 488216
#define WS_PDTF 488216            // ushort[431*21*512] = 2317056 f -> ends 2805272

typedef unsigned short ushort;
typedef __attribute__((ext_vector_type(8))) short short8v;
typedef __attribute__((ext_vector_type(4))) float floatx4;

__device__ __forceinline__ ushort f2bfu(float x) {
  __hip_bfloat16 h = __float2bfloat16(x);
  union { __hip_bfloat16 h; ushort u; } cv; cv.h = h; return cv.u;
}

// ---------------------------------------------------------------------------
// Kernel 0: JvJs accumulation, split over 4 V-chunks, atomicAdd combine.
// ---------------------------------------------------------------------------
__global__ __launch_bounds__(256) void jreg_kernel(
    const float* __restrict__ Jr, const float* __restrict__ vt,
    const float* __restrict__ sd, float* __restrict__ JvJs) {
  const int j = blockIdx.x;
  const int chunk = blockIdx.y;
  const int t = threadIdx.x;
  const int lane = t & 63, wid = t >> 6;
  const int vbeg = chunk * 1723;
  const int vend = (vbeg + 1723 < VNUM) ? vbeg + 1723 : VNUM;
  __shared__ float red[4][33];
  float acc[33];
#pragma unroll
  for (int q = 0; q < 33; q++) acc[q] = 0.0f;
  for (int v = vbeg + t; v < vend; v += 256) {
    float r = Jr[j * VNUM + v];
    const float* vtp = vt + v * 3;
    const float* sdp = sd + v * 30;
    acc[0] += r * vtp[0];
    acc[1] += r * vtp[1];
    acc[2] += r * vtp[2];
#pragma unroll
    for (int q = 0; q < 30; q++) acc[3 + q] += r * sdp[q];
  }
#pragma unroll
  for (int q = 0; q < 33; q++) {
    float x = acc[q];
    for (int off = 32; off > 0; off >>= 1) x += __shfl_down(x, off, 64);
    if (lane == 0) red[wid][q] = x;
  }
  __syncthreads();
  if (t < 33)
    atomicAdd(&JvJs[j * 33 + t], red[0][t] + red[1][t] + red[2][t] + red[3][t]);
}

// ---------------------------------------------------------------------------
// Kernel 1: per-batch: rodrigues, joints_t, chain; writes FRAGMENT-MAJOR
// pfbf[(b>>4)*7+kb][lane*8] (lane=quad*16+(b&15)) and Abff[b][lane*8]
// (lane=quad*16+n, k=quad*8+j, n=12..15 zero).
// pose-feature row: [0..206]=pf, [207..216]=betas, [217..223]=0.
// ---------------------------------------------------------------------------
__global__ __launch_bounds__(64) void batch_prep(
    const float* __restrict__ body_pose, const float* __restrict__ betas,
    const float* __restrict__ global_orient, const float* __restrict__ JvJs,
    float* __restrict__ out_jt, float* __restrict__ out_j, float* __restrict__ out_rm,
    ushort* __restrict__ pfbf, ushort* __restrict__ Abff) {
  const int b = blockIdx.x;
  const int t = threadIdx.x;
  __shared__ float R[24][9];
  __shared__ float jt[24][3];
  __shared__ float chR[24][9];
  __shared__ float cht[24][3];

  if (t < 24) {
    float ax, ay, az;
    if (t == 0) {
      ax = global_orient[b * 3 + 0];
      ay = global_orient[b * 3 + 1];
      az = global_orient[b * 3 + 2];
    } else {
      const float* p = body_pose + (size_t)b * 69 + (t - 1) * 3;
      ax = p[0]; ay = p[1]; az = p[2];
    }
    float px = ax + 1e-8f, py = ay + 1e-8f, pz = az + 1e-8f;
    float angle = sqrtf(px * px + py * py + pz * pz);
    float inv = 1.0f / angle;
    float rx = ax * inv, ry = ay * inv, rz = az * inv;
    float s = sinf(angle), c = cosf(angle);
    float cc = 1.0f - c;
    float m[9];
    m[0] = 1.0f - cc * (ry * ry + rz * rz);
    m[1] = -s * rz + cc * rx * ry;
    m[2] =  s * ry + cc * rx * rz;
    m[3] =  s * rz + cc * rx * ry;
    m[4] = 1.0f - cc * (rx * rx + rz * rz);
    m[5] = -s * rx + cc * ry * rz;
    m[6] = -s * ry + cc * rx * rz;
    m[7] =  s * rx + cc * ry * rz;
    m[8] = 1.0f - cc * (rx * rx + ry * ry);
#pragma unroll
    for (int e = 0; e < 9; e++) {
      R[t][e] = m[e];
      out_rm[(size_t)b * 216 + t * 9 + e] = m[e];
    }
  }
  for (int idx = t; idx < 72; idx += 64) {
    int j = idx / 3, c = idx % 3;
    const float* JJ = JvJs + j * 33;
    float s = JJ[c];
    const float* be = betas + (size_t)b * NBETA;
#pragma unroll
    for (int l = 0; l < NBETA; l++) s += be[l] * JJ[3 + c * 10 + l];
    jt[j][c] = s;
    out_jt[(size_t)b * 72 + idx] = s;
  }
  __syncthreads();
  // pose-feature fragment write: k = mI, dst lane = quad*16 + (b&15)
  for (int mI = t; mI < KPAD; mI += 64) {
    float val = 0.0f;
    if (mI < NPOSE) {
      int k = 1 + mI / 9, e = mI % 9;
      val = R[k][e] - ((e == 0 || e == 4 || e == 8) ? 1.0f : 0.0f);
    } else if (mI < NPOSE + NBETA) {
      val = betas[(size_t)b * NBETA + (mI - NPOSE)];
    }
    int kb = mI >> 5, quad = (mI >> 3) & 3, j = mI & 7;
    pfbf[(size_t)(((b >> 4) * 7 + kb) * 512) + (quad * 16 + (b & 15)) * 8 + j] =
        f2bfu(val);
  }
  if (t == 0) {
    const int par[24] = {-1, 0, 0, 0, 1, 2, 3, 4, 5, 6, 7, 8, 9, 9, 9, 12, 13, 14, 16, 17, 18, 19, 20, 21};
#pragma unroll
    for (int e = 0; e < 9; e++) chR[0][e] = R[0][e];
    cht[0][0] = jt[0][0]; cht[0][1] = jt[0][1]; cht[0][2] = jt[0][2];
    for (int k = 1; k < 24; k++) {
      int p = par[k];
      float rel0 = jt[k][0] - jt[p][0];
      float rel1 = jt[k][1] - jt[p][1];
      float rel2 = jt[k][2] - jt[p][2];
#pragma unroll
      for (int i = 0; i < 3; i++) {
        float a0 = chR[p][i * 3 + 0], a1 = chR[p][i * 3 + 1], a2 = chR[p][i * 3 + 2];
        chR[k][i * 3 + 0] = a0 * R[k][0] + a1 * R[k][3] + a2 * R[k][6];
        chR[k][i * 3 + 1] = a0 * R[k][1] + a1 * R[k][4] + a2 * R[k][7];
        chR[k][i * 3 + 2] = a0 * R[k][2] + a1 * R[k][5] + a2 * R[k][8];
        cht[k][i] = a0 * rel0 + a1 * rel1 + a2 * rel2 + cht[p][i];
      }
    }
  }
  __syncthreads();
  if (t < 24) {
    int k = t;
#pragma unroll
    for (int i = 0; i < 3; i++) out_j[(size_t)b * 72 + k * 3 + i] = cht[k][i];
  }
  // Abff[b*512 + e]: e = (quad*16+n)*8+j, k = quad*8+j; n>=12 or k>=24 -> 0
  for (int e = t; e < 512; e += 64) {
    int quad = e >> 7, n = (e >> 3) & 15, j = e & 7;
    int k = quad * 8 + j;
    float val = 0.0f;
    if (n < 12 && k < 24) {
      int i = n >> 2, jj = n & 3;
      if (jj < 3) {
        val = chR[k][i * 3 + jj];
      } else {
        val = cht[k][i] - (chR[k][i * 3 + 0] * jt[k][0] +
                           chR[k][i * 3 + 1] * jt[k][1] +
                           chR[k][i * 3 + 2] * jt[k][2]);
      }
    }
    Abff[(size_t)b * 512 + e] = f2bfu(val);
  }
}

// ---------------------------------------------------------------------------
// Kernel 2: fragment-major pdTf (k<207 from pd^T, 207..216 from sd, else 0);
// 864 blocks also convert lbs_weights -> fragment-major wbff[vg][lane*8].
// ---------------------------------------------------------------------------
__global__ __launch_bounds__(256) void transpose_pd(
    const float* __restrict__ pd, ushort* __restrict__ pdTf,
    const float* __restrict__ sd,
    const float* __restrict__ w, ushort* __restrict__ wbff) {
  {
    int lb = blockIdx.y * 324 + blockIdx.x;
    if (lb < 864) {                           // 432*512/256 = 864
      int i = lb * 256 + threadIdx.x;
      int vg = i >> 9, e = i & 511;
      int quad = e >> 7, l15 = (e >> 3) & 15, j = e & 7;
      int v = vg * 16 + l15, k = quad * 8 + j;
      float x = (v < VNUM && k < 24) ? w[v * 24 + k] : 0.0f;
      wbff[i] = f2bfu(x);
    }
  }
  __shared__ float tile[32][65];
  const int t = threadIdx.x;
  const int n0 = blockIdx.x * 64;
  const int k0 = blockIdx.y * 32;
  const int c = t & 63;
  for (int r = t >> 6; r < 32; r += 4) {
    int k = k0 + r, n = n0 + c;
    float x = 0.0f;
    if (n < N3) {
      if (k < NPOSE) x = pd[(size_t)k * N3 + n];
      else if (k < NPOSE + NBETA) x = sd[(size_t)n * 10 + (k - NPOSE)];
    }
    tile[r][c] = x;
  }
  __syncthreads();
  const int n = t >> 2;               // local row 0..63
  const int j0 = (t & 3) * 8;         // k offset within 32
  const int rg = n0 + n;              // global row
  if (rg >= NROWF) return;
  unsigned int outw[4];
#pragma unroll
  for (int jj = 0; jj < 4; jj++) {
    unsigned int lo = f2bfu(tile[j0 + jj * 2][n]);
    unsigned int hi = f2bfu(tile[j0 + jj * 2 + 1][n]);
    outw[jj] = lo | (hi << 16);
  }
  const int vg = rg / 48;
  const int rl = rg - vg * 48;
  const int ns = rl >> 4, l15 = rl & 15;
  const int kb = k0 >> 5, quad = j0 >> 3;
  *(uint4*)&pdTf[(size_t)(((vg * 3 + ns) * 7 + kb) * 512) + (quad * 16 + l15) * 8] =
      make_uint4(outw[0], outw[1], outw[2], outw[3]);
}

// ---------------------------------------------------------------------------
// Kernel 3 (fused, v7): cut the per-wave PIPE SUM (R7/R9 showed pipes are
// used ~serially; moving cost between pipes was null — reduce the total):
// - Phase 2 re-partitioned: wave = 8 batches x ALL 4 vgs. Each Abff fragment
//   loaded ONCE (8 VMEM reads, registers; AbS LDS staging deleted) and feeds
//   4 back-to-back MFMAs (one per wf) -> MFMA clustered, dep-wall amortized.
// - vpS per-vertex float4 layout [b][v*4+c], row stride 68 f (<=2-way banks
//   both sides): p-read = 1 aligned ds_read_b128 (was 3 scalar b32).
// - Per-wave LDS ~1200 -> ~530 cyc; LDS 58K -> 34.8K; (256,4) -> 16 waves/CU.
// Phase 1 unchanged from v6 (2 bgroups x 3 ns, bpf shared); one barrier
// (cross-wave vpS). afrag loads issued before the barrier (T14).
// ---------------------------------------------------------------------------
__global__ __launch_bounds__(256, 4) void fused_mfma(
    const ushort* __restrict__ pfbf, const ushort* __restrict__ pdTf,
    const float* __restrict__ vt, const ushort* __restrict__ wbff,
    const ushort* __restrict__ Abff, float* __restrict__ out_v) {
  __shared__ float vpS[4 * 32 * 68];               // 34816 B
  const int tid = threadIdx.x;
  const int lane = tid & 63, wv = tid >> 6;        // 4 waves
  const int l15 = lane & 15, quad = lane >> 4;

  const int bid = blockIdx.x;                      // 3456 = 8*432
  const int L = (bid & 7) * 432 + (bid >> 3);
  const int bt = L & 31;                           // batch tile (fastest)
  const int q  = L >> 5;                           // vg-quad 0..107
  const int bm = bt * 32;                          // block's 32 batches
  const int vg = q * 4 + wv;                       // phase-1 vg of this wave
  const int vgc = (vg < NVG) ? vg : (NVG - 1);

  // wf for all 4 vgs of the block (phase 2); issued early
  short8v wf[4];
#pragma unroll
  for (int v4 = 0; v4 < 4; v4++) {
    int g = q * 4 + v4; if (g >= NVG) g = NVG - 1;
    wf[v4] = *(const short8v*)(wbff + (size_t)g * 512 + lane * 8);
  }
  const int gn0 = vgc * 48 + l15;
  float vt0 = (gn0      < N3) ? vt[gn0]      : 0.0f;
  float vt1 = (gn0 + 16 < N3) ? vt[gn0 + 16] : 0.0f;
  float vt2 = (gn0 + 32 < N3) ? vt[gn0 + 32] : 0.0f;

  // Phase 1: 2 batch-groups x own vg (48 cols); bpf shared across bgroups
  const ushort* apf0 = pfbf + (size_t)((bm >> 4) * 7) * 512 + lane * 8;
  const ushort* apf1 = apf0 + 7 * 512;
  const ushort* bpf  = pdTf + (size_t)(vgc * 21) * 512 + lane * 8;

  const floatx4 zero = {0.0f, 0.0f, 0.0f, 0.0f};
  floatx4 acc[2][3];
#pragma unroll
  for (int bg = 0; bg < 2; bg++)
#pragma unroll
    for (int ns = 0; ns < 3; ns++) acc[bg][ns] = zero;

#pragma unroll
  for (int kb = 0; kb < 7; kb++) {
    short8v a0 = *(const short8v*)(apf0 + kb * 512);
    short8v a1 = *(const short8v*)(apf1 + kb * 512);
    short8v b0 = *(const short8v*)(bpf + (0 * 7 + kb) * 512);
    short8v b1 = *(const short8v*)(bpf + (1 * 7 + kb) * 512);
    short8v b2 = *(const short8v*)(bpf + (2 * 7 + kb) * 512);
    acc[0][0] = __builtin_amdgcn_mfma_f32_16x16x32_bf16(a0, b0, acc[0][0], 0, 0, 0);
    acc[0][1] = __builtin_amdgcn_mfma_f32_16x16x32_bf16(a0, b1, acc[0][1], 0, 0, 0);
    acc[0][2] = __builtin_amdgcn_mfma_f32_16x16x32_bf16(a0, b2, acc[0][2], 0, 0, 0);
    acc[1][0] = __builtin_amdgcn_mfma_f32_16x16x32_bf16(a1, b0, acc[1][0], 0, 0, 0);
    acc[1][1] = __builtin_amdgcn_mfma_f32_16x16x32_bf16(a1, b1, acc[1][1], 0, 0, 0);
    acc[1][2] = __builtin_amdgcn_mfma_f32_16x16x32_bf16(a1, b2, acc[1][2], 0, 0, 0);
  }

  // vpS: per-vertex float4 layout [wv][b][v*4+c], row stride 68 floats
  float* myvp = vpS + wv * 2176;
  int v_[3], c_[3];
#pragma unroll
  for (int ns = 0; ns < 3; ns++) {
    int col = ns * 16 + l15;
    v_[ns] = col / 3;
    c_[ns] = col - v_[ns] * 3;
  }
#pragma unroll
  for (int bg = 0; bg < 2; bg++) {
#pragma unroll
    for (int r = 0; r < 4; r++) {
      int row = bg * 16 + quad * 4 + r;
      myvp[row * 68 + v_[0] * 4 + c_[0]] = acc[bg][0][r] + vt0;
      myvp[row * 68 + v_[1] * 4 + c_[1]] = acc[bg][1][r] + vt1;
      myvp[row * 68 + v_[2] * 4 + c_[2]] = acc[bg][2][r] + vt2;
    }
  }

  // T14 issue-early: this wave's 8 A-fragments (used after the barrier)
  short8v apre[8];
  {
    const ushort* abase = Abff + (size_t)(bm + wv * 8) * 512 + lane * 8;
#pragma unroll
    for (int j = 0; j < 8; j++) apre[j] = *(const short8v*)(abase + j * 512);
  }

  __syncthreads();   // cross-wave vpS visibility

  // Phase 2: wave wv handles batches bm+wv*8..+7 across ALL 4 vgs
  bool act[4];
  int gvv[4];
#pragma unroll
  for (int v4 = 0; v4 < 4; v4++) {
    int vg2 = q * 4 + v4;
    gvv[v4] = vg2 * 16 + l15;
    act[v4] = (quad < 3) && (vg2 < NVG) && (gvv[v4] < VNUM);
  }

#pragma unroll
  for (int i = 0; i < 8; i++) {
    const int b = wv * 8 + i;
    const size_t gb = (size_t)(bm + b);
    short8v afrag = apre[i];
#pragma unroll
    for (int v4 = 0; v4 < 4; v4++) {
      floatx4 t = __builtin_amdgcn_mfma_f32_16x16x32_bf16(afrag, wf[v4], zero, 0, 0, 0);
      const float4 p = *(const float4*)&vpS[v4 * 2176 + b * 68 + l15 * 4];
      if (act[v4]) {
        out_v[gb * N3 + (size_t)gvv[v4] * 3 + quad] =
            t[0] * p.x + t[1] * p.y + t[2] * p.z + t[3];
      }
    }
  }
}

extern "C" void kernel_launch(void* const* d_in, const int* in_sizes, int n_in,
                              void* d_out, int out_size, void* d_ws, size_t ws_size,
                              hipStream_t stream) {
  const float* body_pose     = (const float*)d_in[0];
  const float* betas         = (const float*)d_in[1];
  const float* global_orient = (const float*)d_in[2];
  const float* v_template    = (const float*)d_in[3];
  const float* shapedirs     = (const float*)d_in[4];
  const float* posedirs      = (const float*)d_in[5];
  const float* J_regressor   = (const float*)d_in[6];
  const float* lbs_weights   = (const float*)d_in[7];

  float* out = (float*)d_out;
  float* out_v  = out + OUT_V;
  float* out_jt = out + OUT_JT;
  float* out_j  = out + OUT_J;
  float* out_rm = out + OUT_RM;

  float* ws = (float*)d_ws;
  float* JvJs = ws + WS_JVJS;
  ushort* Abff = (ushort*)(ws + WS_ABFF);
  ushort* wbff = (ushort*)(ws + WS_WBFF);
  ushort* pfbf = (ushort*)(ws + WS_PFBF);
  ushort* pdTf = (ushort*)(ws + WS_PDTF);

  hipMemsetAsync(JvJs, 0, KJ * 33 * sizeof(float), stream);
  jreg_kernel<<<dim3(KJ, 4), 256, 0, stream>>>(J_regressor, v_template, shapedirs, JvJs);
  transpose_pd<<<dim3(324, 7), 256, 0, stream>>>(posedirs, pdTf, shapedirs,
                                                 lbs_weights, wbff);
  batch_prep<<<BATCH, 64, 0, stream>>>(body_pose, betas, global_orient, JvJs,
                                       out_jt, out_j, out_rm, pfbf, Abff);
  fused_mfma<<<3456, 256, 0, stream>>>(pfbf, pdTf, v_template, wbff, Abff, out_v);
}